// Round 7
// baseline (47.727 us; speedup 1.0000x reference)
//
#include <hip/hip_runtime.h>

// NeRF volume compositing, MI355X.
// 2 rays per 64-lane wave (32 lanes/ray), 4 contiguous samples per lane,
// NIT=4 ray-pairs per wave via grid-stride with an explicit A/B load
// pipeline (iteration k+1's global loads fly under iteration k's compute).
//
// T before a sample is the plain exclusive prefix product of (1-a):
// factors in (0,1], T monotone non-increasing, so "dead stays dead"
// truncation == thresholding the prefix product.
//
// Cross-lane work is pure DPP (zero LDS-pipe ops):
//  scan:   row_shr 1/2/4/8 (mul, old=1) + row_bcast15 rm=0xA -> segmented
//          32-lane inclusive product; exclusive via wave_shr:1 + sl==0 fix.
//  reduce: row_shr 1/2/4/8 (add, old=0) + row_bcast15 rm=0xA -> segment
//          sums land in lanes 31 and 63 (the only readers).

#define NIT 4

typedef float f4a __attribute__((ext_vector_type(4), aligned(4)));

template<int CTRL, int RM, unsigned OLD>
__device__ __forceinline__ float dpp_f(float v) {
    return __int_as_float(__builtin_amdgcn_update_dpp(
        (int)OLD, __float_as_int(v), CTRL, RM, 0xF, false));
}

__device__ __forceinline__ float seg_sum32_hi(float v) {
    v += dpp_f<0x111, 0xF, 0u>(v);   // += lane-1 (row_shr:1)
    v += dpp_f<0x112, 0xF, 0u>(v);
    v += dpp_f<0x114, 0xF, 0u>(v);
    v += dpp_f<0x118, 0xF, 0u>(v);   // lanes 15/31/47/63 hold row sums
    v += dpp_f<0x142, 0xA, 0u>(v);   // rows 1,3 += prev row's lane15 sum
    return v;                         // lanes 31/63 = full 32-lane segment sum
}

struct Ld { float4 sg, dt, tt, c0, c1, c2; };

__device__ __forceinline__ Ld load_ray(
    const float* __restrict__ sigmas, const float* __restrict__ deltas,
    const float* __restrict__ ts, const float* __restrict__ rgbs,
    int start, int count, bool inR, int sl, bool fastw)
{
    Ld d;
    if (fastw) {
        // Six independent 16B loads, issued back-to-back.
        d.sg = *(const float4*)(sigmas + start + 4 * sl);
        d.dt = *(const float4*)(deltas + start + 4 * sl);
        d.tt = *(const float4*)(ts     + start + 4 * sl);
        const float* rg = rgbs + 3 * ((size_t)start + 4 * sl);  // 48B-aligned
        d.c0 = *(const float4*)(rg + 0);
        d.c1 = *(const float4*)(rg + 4);
        d.c2 = *(const float4*)(rg + 8);
    } else {
        float sg[4], dt[4], tt[4], rr[4], gg[4], bb[4];
        #pragma unroll
        for (int i = 0; i < 4; ++i) {
            const int s = 4 * sl + i;
            const bool vi = inR && (s < count);
            sg[i] = dt[i] = tt[i] = rr[i] = gg[i] = bb[i] = 0.f;
            if (vi) {
                sg[i] = sigmas[start + s];
                dt[i] = deltas[start + s];
                tt[i] = ts[start + s];
                const float* rg = rgbs + 3 * ((size_t)start + s);
                rr[i] = rg[0]; gg[i] = rg[1]; bb[i] = rg[2];
            }
        }
        d.sg = make_float4(sg[0], sg[1], sg[2], sg[3]);
        d.dt = make_float4(dt[0], dt[1], dt[2], dt[3]);
        d.tt = make_float4(tt[0], tt[1], tt[2], tt[3]);
        d.c0 = make_float4(rr[0], gg[0], bb[0], rr[1]);
        d.c1 = make_float4(gg[1], bb[1], rr[2], gg[2]);
        d.c2 = make_float4(bb[2], rr[3], gg[3], bb[3]);
    }
    return d;
}

__device__ __forceinline__ void compute_ray(
    const Ld& d, int ridx, int start, int count, int ray, bool inR, bool fastw,
    int sl, float thr, float* __restrict__ out, float* __restrict__ cnt_ws,
    int R, int use_ws)
{
    // Invalid lanes have sg=dt=0 -> fe=1 (scan identity); w forced 0 via v[i].
    float fe[4] = { __expf(-d.sg.x * d.dt.x), __expf(-d.sg.y * d.dt.y),
                    __expf(-d.sg.z * d.dt.z), __expf(-d.sg.w * d.dt.w) };
    bool v[4];
    #pragma unroll
    for (int i = 0; i < 4; ++i) v[i] = inR && (4 * sl + i) < count;

    // Segmented 32-lane inclusive prefix product (5 DPP muls, old=1).
    const float fprod = (fe[0] * fe[1]) * (fe[2] * fe[3]);
    float inc = fprod;
    inc *= dpp_f<0x111, 0xF, 0x3f800000u>(inc);   // row_shr:1
    inc *= dpp_f<0x112, 0xF, 0x3f800000u>(inc);
    inc *= dpp_f<0x114, 0xF, 0x3f800000u>(inc);
    inc *= dpp_f<0x118, 0xF, 0x3f800000u>(inc);
    inc *= dpp_f<0x142, 0xA, 0x3f800000u>(inc);   // row_bcast15 -> rows 1,3

    // Exclusive prefix: wave_shr:1 (lane l <- inc[l-1]); segment heads -> 1.
    float ex = dpp_f<0x138, 0xF, 0x3f800000u>(inc);
    float T = (sl == 0) ? 1.f : ex;

    float w[4];
    float cnt = 0.f;
    #pragma unroll
    for (int i = 0; i < 4; ++i) {
        const bool alive = v[i] && (T > thr);
        const float Tn = T * fe[i];
        w[i] = alive ? (T - Tn) : 0.f;
        cnt += alive ? 1.f : 0.f;
        T = Tn;
    }

    // Per-sample weights (ws base is odd floats -> 4B-aligned wide store).
    float* wsp = out + 1 + 5 * (size_t)R + (size_t)start + 4 * sl;
    if (fastw) {
        f4a wv; wv.x = w[0]; wv.y = w[1]; wv.z = w[2]; wv.w = w[3];
        *(f4a*)wsp = wv;
    } else {
        #pragma unroll
        for (int i = 0; i < 4; ++i) if (v[i]) wsp[i] = w[i];
    }

    float op  = (w[0] + w[1]) + (w[2] + w[3]);
    float dep = fmaf(w[0], d.tt.x, fmaf(w[1], d.tt.y, fmaf(w[2], d.tt.z, w[3] * d.tt.w)));
    float cr  = fmaf(w[0], d.c0.x, fmaf(w[1], d.c0.w, fmaf(w[2], d.c1.z, w[3] * d.c2.y)));
    float cg  = fmaf(w[0], d.c0.y, fmaf(w[1], d.c1.x, fmaf(w[2], d.c1.w, w[3] * d.c2.z)));
    float cb  = fmaf(w[0], d.c0.z, fmaf(w[1], d.c1.y, fmaf(w[2], d.c2.x, w[3] * d.c2.w)));

    op  = seg_sum32_hi(op);
    dep = seg_sum32_hi(dep);
    cr  = seg_sum32_hi(cr);
    cg  = seg_sum32_hi(cg);
    cb  = seg_sum32_hi(cb);
    cnt = seg_sum32_hi(cnt);

    if (sl == 31 && inR) {
        out[1 + ridx]                 = op;
        out[1 + R + ridx]             = dep;
        out[1 + 2 * R + 3 * ridx + 0] = cr;
        out[1 + 2 * R + 3 * ridx + 1] = cg;
        out[1 + 2 * R + 3 * ridx + 2] = cb;
        if (use_ws) cnt_ws[ray] = cnt;
        else        atomicAdd(&out[0], cnt);
    }
}

__global__ __launch_bounds__(256) void vr_main(
    const float* __restrict__ sigmas, const float* __restrict__ rgbs,
    const float* __restrict__ deltas, const float* __restrict__ ts,
    const int* __restrict__ rays_a, const float* __restrict__ thr_p,
    float* __restrict__ out, float* __restrict__ cnt_ws,
    int R, int use_ws)
{
    const int wib  = (int)(threadIdx.x >> 6);
    const int lane = (int)(threadIdx.x & 63);
    const int half = lane >> 5;
    const int sl   = lane & 31;
    const int wid  = (int)blockIdx.x * 4 + wib;
    const int wpg  = (int)gridDim.x * 4;     // waves per grid
    const float thr = thr_p[0];

    // Ray metadata for all NIT iterations upfront (independent loads).
    int ridx[NIT], start[NIT], count[NIT], rayk[NIT];
    bool inR[NIT], fw[NIT];
    #pragma unroll
    for (int k = 0; k < NIT; ++k) {
        const int ray = 2 * (wid + k * wpg) + half;
        rayk[k] = ray;
        inR[k] = ray < R;
        ridx[k] = start[k] = count[k] = 0;
        if (inR[k]) {
            ridx[k]  = rays_a[3 * ray + 0];
            start[k] = rays_a[3 * ray + 1];
            count[k] = rays_a[3 * ray + 2];
        }
    }
    #pragma unroll
    for (int k = 0; k < NIT; ++k)
        fw[k] = __all(inR[k] && (count[k] == 128) && ((start[k] & 3) == 0));

    // Software pipeline: loads for k+1 in flight under compute of k.
    Ld A = load_ray(sigmas, deltas, ts, rgbs, start[0], count[0], inR[0], sl, fw[0]);
    #pragma unroll
    for (int k = 0; k < NIT; ++k) {
        if (k + 1 < NIT) {
            Ld B = load_ray(sigmas, deltas, ts, rgbs,
                            start[k + 1], count[k + 1], inR[k + 1], sl, fw[k + 1]);
            compute_ray(A, ridx[k], start[k], count[k], rayk[k], inR[k], fw[k],
                        sl, thr, out, cnt_ws, R, use_ws);
            A = B;
        } else {
            compute_ray(A, ridx[k], start[k], count[k], rayk[k], inR[k], fw[k],
                        sl, thr, out, cnt_ws, R, use_ws);
        }
    }
}

// Single block: full sum of cnt_ws -> plain store to out[0] (overwrites
// poison deterministically every replay; no memset needed).
__global__ __launch_bounds__(1024) void vr_total(
    const float* __restrict__ cnt_ws, float* __restrict__ out, int R)
{
    __shared__ float sm[16];
    float s = 0.f;
    const int R4 = R & ~3;
    for (int i = (int)threadIdx.x * 4; i < R4; i += 4096) {
        const float4 c = *(const float4*)(cnt_ws + i);
        s += (c.x + c.y) + (c.z + c.w);
    }
    if (threadIdx.x == 0)
        for (int i = R4; i < R; ++i) s += cnt_ws[i];
    #pragma unroll
    for (int d = 32; d; d >>= 1) s += __shfl_xor(s, d, 64);
    if ((threadIdx.x & 63) == 0) sm[threadIdx.x >> 6] = s;
    __syncthreads();
    if (threadIdx.x == 0) {
        float t = 0.f;
        #pragma unroll
        for (int k = 0; k < 16; ++k) t += sm[k];
        out[0] = t;
    }
}

extern "C" void kernel_launch(void* const* d_in, const int* in_sizes, int n_in,
                              void* d_out, int out_size, void* d_ws, size_t ws_size,
                              hipStream_t stream) {
    const float* sigmas = (const float*)d_in[0];
    const float* rgbs   = (const float*)d_in[1];
    const float* deltas = (const float*)d_in[2];
    const float* ts     = (const float*)d_in[3];
    const int*   rays_a = (const int*)d_in[4];
    const float* thr    = (const float*)d_in[5];
    int R = in_sizes[4] / 3;
    float* out = (float*)d_out;
    float* cnt_ws = (float*)d_ws;

    int use_ws = (ws_size >= (size_t)R * sizeof(float)) ? 1 : 0;

    if (!use_ws)  // atomic fallback needs a zero seed for out[0]
        hipMemsetAsync(d_out, 0, 4, stream);

    // 4 waves/block x 2 rays/wave x NIT ray-pairs per wave.
    const int raysPerBlock = 8 * NIT;
    int grid = (R + raysPerBlock - 1) / raysPerBlock;
    vr_main<<<grid, 256, 0, stream>>>(sigmas, rgbs, deltas, ts, rays_a, thr,
                                      out, cnt_ws, R, use_ws);
    if (use_ws)
        vr_total<<<1, 1024, 0, stream>>>(cnt_ws, out, R);
}